// Round 1
// baseline (183.413 us; speedup 1.0000x reference)
//
#include <hip/hip_runtime.h>
#include <hip/hip_bf16.h>

// GMM log-prob: out[n,k] = -0.5*(D*log(2pi) + ||x_n L_k - mu_k L_k||^2) + sum(log(diag(L_k)))
// N=16384, K=200, D=64. Strategy: bf16 MFMA GEMM (y = x @ L_k) fused with
// squared-distance reduction. Block = 256 thr (4 waves) covers 128 rows x 2 k;
// each wave does one 64x64 y-tile for one k with 32x mfma_f32_16x16x32_bf16.

#define K_COMP 200
#define XPITCH 72   // 64 + 8 bf16 pad: keeps 16B alignment, 2-way bank alias only
#define LPITCH 72

typedef __bf16 bf16x8 __attribute__((ext_vector_type(8)));
typedef float  f32x4  __attribute__((ext_vector_type(4)));

__global__ __launch_bounds__(256) void gmm_logprob(
    const float* __restrict__ x,
    const float* __restrict__ means,
    const float* __restrict__ prec,
    float* __restrict__ out)
{
    __shared__ __align__(16) __bf16 sX[128 * XPITCH];      // x tile [row][d]
    __shared__ __align__(16) __bf16 sL[2][64 * LPITCH];    // L_k transposed: [e][d]
    __shared__ __align__(16) float  sMu[2][64];            // mu_k @ L_k
    __shared__ float sLd[2];                               // logdet per k
    __shared__ __align__(16) float sOutT[2][128];          // ssq, transposed for coalesced store

    const int tid    = threadIdx.x;
    const int n_base = blockIdx.x * 128;
    const int k_base = blockIdx.y * 2;

    // ---- stage x tile as bf16 (coalesced float4 reads) ----
    {
        const float4* xs = (const float4*)(x + (size_t)n_base * 64);
        #pragma unroll
        for (int it = 0; it < 8; ++it) {
            int f4 = it * 256 + tid;          // 0..2047 (128 rows * 16 float4)
            float4 v = xs[f4];
            int r = f4 >> 4;
            int c = (f4 & 15) * 4;
            __bf16* dst = &sX[r * XPITCH + c];
            dst[0] = (__bf16)v.x; dst[1] = (__bf16)v.y;
            dst[2] = (__bf16)v.z; dst[3] = (__bf16)v.w;
        }
    }
    // ---- stage prec_chol (2 k's), transposed to [e][d] so B-frags are contiguous ----
    {
        #pragma unroll
        for (int it = 0; it < 8; ++it) {
            int f4  = it * 256 + tid;         // 0..2047 (2 k * 1024 float4)
            int kk  = f4 >> 10;
            int rem = f4 & 1023;
            const float4* ps = (const float4*)(prec + (size_t)(k_base + kk) * 4096);
            float4 v = ps[rem];
            int d  = rem >> 4;                // 0..63
            int e0 = (rem & 15) * 4;
            __bf16* b = sL[kk];
            b[(e0 + 0) * LPITCH + d] = (__bf16)v.x;
            b[(e0 + 1) * LPITCH + d] = (__bf16)v.y;
            b[(e0 + 2) * LPITCH + d] = (__bf16)v.z;
            b[(e0 + 3) * LPITCH + d] = (__bf16)v.w;
        }
    }
    __syncthreads();

    // ---- mu_prec[k,e] + logdet[k]: waves 0,1 (one wave per k); waves 2,3 go straight to MFMA ----
    if (tid < 128) {
        int kk = tid >> 6;
        int e  = tid & 63;
        const float*  mk   = means + (size_t)(k_base + kk) * 64;
        const __bf16* lrow = &sL[kk][e * LPITCH];
        float accm = 0.f;
        #pragma unroll
        for (int j = 0; j < 8; ++j) {
            bf16x8 lv = *(const bf16x8*)(lrow + j * 8);
            #pragma unroll
            for (int i = 0; i < 8; ++i)
                accm += mk[j * 8 + i] * (float)lv[i];
        }
        sMu[kk][e] = accm;
        float ld = __logf(prec[(size_t)(k_base + kk) * 4096 + (size_t)e * 64 + e]);
        #pragma unroll
        for (int m = 32; m >= 1; m >>= 1)
            ld += __shfl_xor(ld, m, 64);
        if (e == 0) sLd[kk] = ld;
    }

    // ---- MFMA main: wave = (n_half, kk); 64 rows x 64 e-cols per wave ----
    const int wave   = tid >> 6;
    const int lane   = tid & 63;
    const int n_half = wave >> 1;
    const int kk     = wave & 1;
    const int li     = lane & 15;
    const int q      = lane >> 4;

    f32x4 acc[4][4];
    #pragma unroll
    for (int a = 0; a < 4; ++a)
        #pragma unroll
        for (int b = 0; b < 4; ++b)
            acc[a][b] = (f32x4){0.f, 0.f, 0.f, 0.f};

    const __bf16* xb = &sX[(n_half * 64 + li) * XPITCH];   // A row = m = lane&15 (+16*tm)
    const __bf16* lb = &sL[kk][li * LPITCH];               // B col = n = lane&15 (+16*te)

    #pragma unroll
    for (int ks = 0; ks < 2; ++ks) {
        bf16x8 af[4], bfr[4];
        #pragma unroll
        for (int t = 0; t < 4; ++t)
            af[t]  = *(const bf16x8*)(xb + t * 16 * XPITCH + ks * 32 + q * 8);
        #pragma unroll
        for (int t = 0; t < 4; ++t)
            bfr[t] = *(const bf16x8*)(lb + t * 16 * LPITCH + ks * 32 + q * 8);
        #pragma unroll
        for (int tm = 0; tm < 4; ++tm)
            #pragma unroll
            for (int te = 0; te < 4; ++te)
                acc[tm][te] = __builtin_amdgcn_mfma_f32_16x16x32_bf16(
                    af[tm], bfr[te], acc[tm][te], 0, 0, 0);
    }
    __syncthreads();   // sMu/sLd now visible; all frag reads drained

    // ---- epilogue: ssq[row] = sum_e (y - mu)^2 ----
    float muv[4];
    #pragma unroll
    for (int te = 0; te < 4; ++te) muv[te] = sMu[kk][te * 16 + li];

    #pragma unroll
    for (int tm = 0; tm < 4; ++tm) {
        float v0 = 0.f, v1 = 0.f, v2 = 0.f, v3 = 0.f;
        #pragma unroll
        for (int te = 0; te < 4; ++te) {
            f32x4 a = acc[tm][te];
            float mu = muv[te];
            float d0 = a[0] - mu; v0 += d0 * d0;
            float d1 = a[1] - mu; v1 += d1 * d1;
            float d2 = a[2] - mu; v2 += d2 * d2;
            float d3 = a[3] - mu; v3 += d3 * d3;
        }
        // reduce over the 16 column-lanes (masks < 16 keep q fixed)
        #pragma unroll
        for (int m = 1; m <= 8; m <<= 1) {
            v0 += __shfl_xor(v0, m, 64);
            v1 += __shfl_xor(v1, m, 64);
            v2 += __shfl_xor(v2, m, 64);
            v3 += __shfl_xor(v3, m, 64);
        }
        if (li == 0) {
            // rows tm*16 + q*4 + {0..3} are consecutive -> float4 store
            *(float4*)&sOutT[kk][n_half * 64 + tm * 16 + q * 4] = make_float4(v0, v1, v2, v3);
        }
    }
    __syncthreads();

    // ---- final: coalesced-ish float2 stores, 128 threads ----
    if (tid < 128) {
        const float cbase = -0.5f * 64.0f * 1.8378770664093453f;  // -0.5*D*log(2pi)
        float2 o;
        o.x = cbase - 0.5f * sOutT[0][tid] + sLd[0];
        o.y = cbase - 0.5f * sOutT[1][tid] + sLd[1];
        *(float2*)(out + (size_t)(n_base + tid) * K_COMP + k_base) = o;
    }
}

extern "C" void kernel_launch(void* const* d_in, const int* in_sizes, int n_in,
                              void* d_out, int out_size, void* d_ws, size_t ws_size,
                              hipStream_t stream) {
    const float* x     = (const float*)d_in[0];   // [16384, 64]
    const float* means = (const float*)d_in[1];   // [200, 64]
    const float* prec  = (const float*)d_in[2];   // [200, 64, 64]
    float* out = (float*)d_out;                   // [16384, 200]
    dim3 grid(16384 / 128, 200 / 2);
    gmm_logprob<<<grid, 256, 0, stream>>>(x, means, prec, out);
}

// Round 2
// 125.053 us; speedup vs baseline: 1.4667x; 1.4667x over previous
//
#include <hip/hip_runtime.h>
#include <hip/hip_bf16.h>
#include <stdint.h>

typedef __bf16 bf16x8 __attribute__((ext_vector_type(8)));
typedef float  f32x4  __attribute__((ext_vector_type(4)));

#define KC 200
#define CBASE (-58.8120661251f)   // -0.5 * 64 * log(2*pi)

// ws layout:
//   Lt  : bf16 [200][64][64]  ([k][e][d])   bytes        0 .. 1638400
//   muL : f32  [200][64]                    1638400 .. 1689600
//   ck  : f32  [200]                        1689600 .. 1690400

// ---------------- prepass: transpose/convert prec, compute muL + ck ----------------
__global__ __launch_bounds__(256) void prep_b(const float* __restrict__ prec,
                                              const float* __restrict__ means,
                                              __bf16* __restrict__ Lt,
                                              float* __restrict__ muL,
                                              float* __restrict__ ck) {
    __shared__ float sP[64][68];   // [d][e], pad 4 floats
    __shared__ float sM[64];
    const int k = blockIdx.x, tid = threadIdx.x;
    const float* pk = prec + (size_t)k * 4096;
    #pragma unroll
    for (int it = 0; it < 4; ++it) {
        int f4 = tid + it * 256;          // 1024 float4 = 64x64
        float4 v = ((const float4*)pk)[f4];
        int d = f4 >> 4, e0 = (f4 & 15) * 4;
        *(float4*)&sP[d][e0] = v;
    }
    if (tid < 16) *(float4*)&sM[tid * 4] = ((const float4*)(means + (size_t)k * 64))[tid];
    __syncthreads();
    // Lt[k][e][d] = prec[k][d][e], bf16
    #pragma unroll
    for (int it = 0; it < 2; ++it) {
        int c = tid + it * 256;           // 512 chunks of 8
        int e = c >> 3, d0 = (c & 7) * 8;
        bf16x8 o;
        #pragma unroll
        for (int i = 0; i < 8; ++i) o[i] = (__bf16)sP[d0 + i][e];
        *(bf16x8*)(Lt + (size_t)k * 4096 + e * 64 + d0) = o;
    }
    if (tid < 64) {
        int e = tid;
        float m = 0.f;
        #pragma unroll 8
        for (int d = 0; d < 64; ++d) m += sM[d] * sP[d][e];
        muL[k * 64 + e] = m;
        float l = __logf(sP[e][e]);
        #pragma unroll
        for (int mm = 32; mm >= 1; mm >>= 1) l += __shfl_xor(l, mm, 64);
        if (e == 0) ck[k] = l + CBASE;
    }
}

// ---------------- main: fused GEMM + squared-distance ----------------
#define GLL16(gp_, lp_) \
    __builtin_amdgcn_global_load_lds((__attribute__((address_space(1))) const void*)(gp_), \
                                     (__attribute__((address_space(3))) void*)(lp_), 16, 0, 0)

__global__ __launch_bounds__(256, 3) void gmm_main(const float* __restrict__ x,
                                                   const __bf16* __restrict__ Lt,
                                                   const float* __restrict__ muL,
                                                   const float* __restrict__ ck,
                                                   float* __restrict__ out) {
    // buf(2) x kk(2) x 4096 bf16; rows of 64 bf16 (128B), seg-swizzled: seg' = seg ^ (e&7)
    __shared__ __align__(16) __bf16 sB[2 * 2 * 4096];
    __shared__ float sMu[1280];     // muL for this 20-k chunk

    const int tid  = threadIdx.x;
    const int wave = tid >> 6, lane = tid & 63;
    const int li   = lane & 15, q = lane >> 4;
    const int r8   = lane >> 3, s8 = lane & 7;    // staging decomposition
    const int row0 = blockIdx.x * 256 + wave * 64;
    const int k0   = blockIdx.y * 20;
    char* sBc = (char*)sB;

    // --- issue stage of group 0 (k0, k0+1) into buf 0 ---
    {
        const __bf16* LtK = Lt + (size_t)k0 * 4096;
        #pragma unroll
        for (int i = 0; i < 4; ++i) {
            int t = wave * 4 + i;                 // 16 insts cover 16 KB
            int kk = t >> 3, rb = (t & 7) * 8;
            GLL16(LtK + kk * 4096 + (rb + r8) * 64 + (s8 ^ r8) * 8,
                  sBc + kk * 8192 + (t & 7) * 1024);
        }
    }
    // --- stage muL chunk (1280 f32) ---
    for (int idx = tid; idx < 1280; idx += 256) sMu[idx] = muL[k0 * 64 + idx];

    // --- A fragments (64 rows per wave) straight from x, f32 -> bf16 in regs ---
    bf16x8 af[4][2];
    #pragma unroll
    for (int tm = 0; tm < 4; ++tm) {
        const float* xr = x + (size_t)(row0 + 16 * tm + li) * 64 + q * 8;
        #pragma unroll
        for (int ks = 0; ks < 2; ++ks) {
            float4 v0 = *(const float4*)(xr + ks * 32);
            float4 v1 = *(const float4*)(xr + ks * 32 + 4);
            bf16x8 a;
            a[0] = (__bf16)v0.x; a[1] = (__bf16)v0.y; a[2] = (__bf16)v0.z; a[3] = (__bf16)v0.w;
            a[4] = (__bf16)v1.x; a[5] = (__bf16)v1.y; a[6] = (__bf16)v1.z; a[7] = (__bf16)v1.w;
            af[tm][ks] = a;
        }
    }

    float* outw = out + (size_t)row0 * KC + k0;

    for (int gp = 0; gp < 5; ++gp) {
        f32x4 res4[4];
        #pragma unroll
        for (int g2 = 0; g2 < 2; ++g2) {
            __syncthreads();   // drains stage(g) [issued last iter] + all waves done with buf g2^1
            // prefetch group g+1 into other buffer (in flight across compute, NOT drained here)
            if (g2 == 0 || gp < 4) {
                const __bf16* LtN = Lt + (size_t)(k0 + (gp * 2 + g2 + 1) * 2) * 4096;
                char* dstb = sBc + (g2 ^ 1) * 16384;
                #pragma unroll
                for (int i = 0; i < 4; ++i) {
                    int t = wave * 4 + i;
                    int kk = t >> 3, rb = (t & 7) * 8;
                    GLL16(LtN + kk * 4096 + (rb + r8) * 64 + (s8 ^ r8) * 8,
                          dstb + kk * 8192 + (t & 7) * 1024);
                }
            }
            #pragma unroll
            for (int kk = 0; kk < 2; ++kk) {
                const int rc = g2 * 2 + kk;            // res component (compile-time)
                const int krbase = gp * 4 + g2 * 2 + kk;
                char* bufb = sBc + g2 * 16384 + kk * 8192;
                // B fragments: e-row = 16te+li, seg = (ks*4+q) ^ (li&7)  -> 2-way max (free)
                bf16x8 bfr[4][2];
                #pragma unroll
                for (int te = 0; te < 4; ++te) {
                    int e = 16 * te + li;
                    #pragma unroll
                    for (int ks = 0; ks < 2; ++ks) {
                        int seg = (ks * 4 + q) ^ (li & 7);
                        bfr[te][ks] = *(const bf16x8*)(bufb + e * 128 + seg * 16);
                    }
                }
                f32x4 acc[4][4];
                #pragma unroll
                for (int tm = 0; tm < 4; ++tm)
                    #pragma unroll
                    for (int te = 0; te < 4; ++te) {
                        acc[tm][te] = __builtin_amdgcn_mfma_f32_16x16x32_bf16(
                            af[tm][0], bfr[te][0], (f32x4){0.f, 0.f, 0.f, 0.f}, 0, 0, 0);
                        acc[tm][te] = __builtin_amdgcn_mfma_f32_16x16x32_bf16(
                            af[tm][1], bfr[te][1], acc[tm][te], 0, 0, 0);
                    }
                float muv[4];
                #pragma unroll
                for (int te = 0; te < 4; ++te) muv[te] = sMu[krbase * 64 + te * 16 + li];
                // epilogue: ssq rowsums via reduce-scatter (8 shfl + 8 add per tm)
                #pragma unroll
                for (int tm = 0; tm < 4; ++tm) {
                    float v0 = 0.f, v1 = 0.f, v2 = 0.f, v3 = 0.f;
                    #pragma unroll
                    for (int te = 0; te < 4; ++te) {
                        f32x4 a = acc[tm][te];
                        float mu = muv[te];
                        float d0 = a[0] - mu, d1 = a[1] - mu, d2 = a[2] - mu, d3 = a[3] - mu;
                        v0 = fmaf(d0, d0, v0); v1 = fmaf(d1, d1, v1);
                        v2 = fmaf(d2, d2, v2); v3 = fmaf(d3, d3, v3);
                    }
                    float a0 = v0 + __shfl_xor(v0, 1, 64);
                    float a1 = v1 + __shfl_xor(v1, 1, 64);
                    float a2 = v2 + __shfl_xor(v2, 1, 64);
                    float a3 = v3 + __shfl_xor(v3, 1, 64);
                    bool o1 = (li & 1);
                    float p  = o1 ? a2 : a0;
                    float rr = o1 ? a3 : a1;
                    float b0 = p  + __shfl_xor(p, 2, 64);
                    float b1 = rr + __shfl_xor(rr, 2, 64);
                    float s  = (li & 2) ? b1 : b0;
                    s += __shfl_xor(s, 4, 64);
                    s += __shfl_xor(s, 8, 64);
                    // lane (q, li): s = rowsum of row 16tm + 4q + (2*(li&1) + ((li>>1)&1))
                    res4[tm][rc] = s;
                }
            } // kk
        } // g2
        // store 4 k-columns (k0 + gp*4 .. +3), float4, lanes li<4 per quad
        {
            f32x4 ckv = *(const f32x4*)(ck + k0 + gp * 4);
            if (li < 4) {
                int R = 4 * q + 2 * (li & 1) + ((li >> 1) & 1);
                #pragma unroll
                for (int tm = 0; tm < 4; ++tm) {
                    f32x4 o;
                    #pragma unroll
                    for (int c = 0; c < 4; ++c) o[c] = fmaf(-0.5f, res4[tm][c], ckv[c]);
                    *(f32x4*)(outw + (size_t)(16 * tm + R) * KC + gp * 4) = o;
                }
            }
        }
    } // gp
}

extern "C" void kernel_launch(void* const* d_in, const int* in_sizes, int n_in,
                              void* d_out, int out_size, void* d_ws, size_t ws_size,
                              hipStream_t stream) {
    const float* x     = (const float*)d_in[0];   // [16384, 64]
    const float* means = (const float*)d_in[1];   // [200, 64]
    const float* prec  = (const float*)d_in[2];   // [200, 64, 64]
    float* out = (float*)d_out;                   // [16384, 200]

    __bf16* Lt  = (__bf16*)d_ws;
    float*  muL = (float*)((char*)d_ws + 1638400);
    float*  ckp = (float*)((char*)d_ws + 1689600);

    prep_b<<<200, 256, 0, stream>>>(prec, means, Lt, muL, ckp);
    gmm_main<<<dim3(64, 10), 256, 0, stream>>>(x, Lt, muL, ckp, out);
}